// Round 3
// baseline (408.140 us; speedup 1.0000x reference)
//
#include <hip/hip_runtime.h>
#include <hip/hip_bf16.h>
#include <stdint.h>

#define NQ 4096
#define NK 2048

typedef __bf16 bf16x8 __attribute__((ext_vector_type(8)));
typedef __bf16 bf16x4 __attribute__((ext_vector_type(4)));
typedef float floatx4 __attribute__((ext_vector_type(4)));

// Raw barrier + partial vmcnt wait: prefetch loads stay in flight across the barrier.
#define WAITB(N) asm volatile("s_waitcnt vmcnt(" #N ")\n\ts_barrier" ::: "memory")
#define BAR()    asm volatile("s_barrier" ::: "memory")
#define LBAR()   asm volatile("s_waitcnt lgkmcnt(0)\n\ts_barrier" ::: "memory")

__device__ __forceinline__ void async_ld16(const void* g, void* l) {
  __builtin_amdgcn_global_load_lds((const __attribute__((address_space(1))) void*)g,
                                   (__attribute__((address_space(3))) void*)l, 16, 0, 0);
}

// ---------------- Convert weights AND activations f32 -> bf16 ----------------
// Wq/Wk/Wv -> Wbf (workspace); queries/keys/values -> Xbf (scratch in d_out A2 region,
// dead until attn_mean which is the last kernel).
__global__ __launch_bounds__(256) void cvt_all(
    const float* __restrict__ Wq, const float* __restrict__ Wk, const float* __restrict__ Wv,
    const float* __restrict__ Xq, const float* __restrict__ Xk, const float* __restrict__ Xv,
    __bf16* __restrict__ Wbf, __bf16* __restrict__ Xbf)
{
  int bid = blockIdx.x;
  const float* src; __bf16* dst; int lb;
  if (bid < 3072)       { int seg = bid >> 10;
                          src = seg == 0 ? Wq : (seg == 1 ? Wk : Wv);
                          dst = Wbf + (size_t)seg * 1048576; lb = bid & 1023; }
  else if (bid < 11264) { src = Xq; dst = Xbf;            lb = bid - 3072;  }  // 8192 blocks
  else if (bid < 15360) { src = Xk; dst = Xbf + 8388608;  lb = bid - 11264; }  // 4096 blocks
  else                  { src = Xv; dst = Xbf + 12582912; lb = bid - 15360; }  // 4096 blocks
  int idx = (lb * 256 + threadIdx.x) * 4;
  float4 v = *(const float4*)(src + idx);
  bf16x4 o;
  o[0] = (__bf16)v.x; o[1] = (__bf16)v.y; o[2] = (__bf16)v.z; o[3] = (__bf16)v.w;
  *(bf16x4*)(dst + idx) = o;
}

// ---------------- Merged projection GEMM: Q/K/V in one launch, pure bf16 ----------------
// m97-verified structure: both operands via 16B global_load_lds, 8 ds_read_b128 +
// 16 MFMA per K-step, 32KB LDS total (4 blocks/CU).
__device__ __forceinline__ void stage_ab(const __bf16* __restrict__ A, const __bf16* __restrict__ W,
                                         int bm, int bn, int k0, bf16x8* As, bf16x8* Bs, int t) {
#pragma unroll
  for (int s2 = 0; s2 < 2; ++s2) {
    int s = s2 * 256 + t;
    int r = s >> 2, kb = (s & 3) ^ ((r >> 1) & 3);   // 128 rows x 4 chunks of 8 bf16
    async_ld16(A + (size_t)(bm + r) * 1024 + k0 + kb * 8, &As[s2 * 256 + (t & ~63)]);
    async_ld16(W + (size_t)(bn + r) * 1024 + k0 + kb * 8, &Bs[s2 * 256 + (t & ~63)]);
  }
}

__global__ __launch_bounds__(256, 4) void gemm_all(
    const __bf16* __restrict__ Xq, const __bf16* __restrict__ Xk, const __bf16* __restrict__ Xv,
    const __bf16* __restrict__ Wbf,
    const float* __restrict__ bq, const float* __restrict__ bk, const float* __restrict__ bv,
    __bf16* __restrict__ Qp, __bf16* __restrict__ Kp, __bf16* __restrict__ Vt)
{
  __shared__ bf16x8 As[2][512];
  __shared__ bf16x8 Bs[2][512];
  const int t = threadIdx.x, wid = t >> 6, lane = t & 63;
  const int g = lane >> 4, c = lane & 15;
  const int mt = blockIdx.x;
  const __bf16* A; const __bf16* W; const float* bias; __bf16* Y; int bm; bool vmode;
  if (mt < 64)      { A = Xq; W = Wbf;           bias = bq; Y = Qp; bm = mt * 128;        vmode = false; }
  else if (mt < 96) { A = Xk; W = Wbf + 1048576; bias = bk; Y = Kp; bm = (mt - 64) * 128; vmode = false; }
  else              { A = Xv; W = Wbf + 2097152; bias = bv; Y = Vt; bm = (mt - 96) * 128; vmode = true;  }
  const int bn = blockIdx.y * 128;
  const int m_off = (wid >> 1) * 64, n_off = (wid & 1) * 64;
  floatx4 acc[4][4] = {};
  const int swz = g ^ ((c >> 1) & 3);
  stage_ab(A, W, bm, bn, 0, &As[0][0], &Bs[0][0], t);
  for (int k0 = 0; k0 < 1024; k0 += 32) {
    int cur = (k0 >> 5) & 1;
    if (k0 + 32 < 1024) { stage_ab(A, W, bm, bn, k0 + 32, &As[cur ^ 1][0], &Bs[cur ^ 1][0], t); WAITB(4); }
    else WAITB(0);
    bf16x8 af[4], bfr[4];
#pragma unroll
    for (int mb = 0; mb < 4; ++mb) af[mb] = As[cur][(m_off + mb * 16 + c) * 4 + swz];
#pragma unroll
    for (int nb = 0; nb < 4; ++nb) bfr[nb] = Bs[cur][(n_off + nb * 16 + c) * 4 + swz];
#pragma unroll
    for (int mb = 0; mb < 4; ++mb)
#pragma unroll
      for (int nb = 0; nb < 4; ++nb)
        acc[mb][nb] = __builtin_amdgcn_mfma_f32_16x16x32_bf16(af[mb], bfr[nb], acc[mb][nb], 0, 0, 0);
    BAR();
  }
#pragma unroll
  for (int nb = 0; nb < 4; ++nb) {
    int col = bn + n_off + nb * 16 + c;
    float bv2 = bias[col];
    if (!vmode) {
#pragma unroll
      for (int mb = 0; mb < 4; ++mb)
#pragma unroll
        for (int reg = 0; reg < 4; ++reg) {
          int row = bm + m_off + mb * 16 + g * 4 + reg;
          Y[(size_t)row * 1024 + col] = (__bf16)(acc[mb][nb][reg] + bv2);
        }
    } else {
      // Vt[(b*8+h)*128 + d][j]; col = h*128+d, row = b*2048+j. 4 regs = 4 consecutive j.
#pragma unroll
      for (int mb = 0; mb < 4; ++mb) {
        int row0 = bm + m_off + mb * 16 + g * 4;
        bf16x4 pv;
#pragma unroll
        for (int reg = 0; reg < 4; ++reg) pv[reg] = (__bf16)(acc[mb][nb][reg] + bv2);
        *(bf16x4*)&Y[(size_t)((row0 >> 11) * 1024 + col) * 2048 + (row0 & 2047)] = pv;
      }
    }
  }
}

// ---------------- Flash pass 1: m==0 softmax, 128-row Q tile, P overlays K region ----------
__device__ __forceinline__ void stage_kv(const __bf16* __restrict__ Kp, const __bf16* __restrict__ Vt,
                                         int b, int h, int j0, bf16x8* buf, int t) {
#pragma unroll
  for (int s4 = 0; s4 < 4; ++s4) {
    int s = s4 * 256 + t;
    int j = s >> 4, db = (s & 15) ^ (j & 15);     // K: 64 rows(j) x 16 chunks(d)
    async_ld16(Kp + (size_t)(b * NK + j0 + j) * 1024 + h * 128 + db * 8, &buf[s4 * 256 + (t & ~63)]);
    int d = s >> 3, kb = (s & 7) ^ (d & 7);       // V: 128 rows(d) x 8 chunks(j)
    async_ld16(Vt + (size_t)((b * 8 + h) * 128 + d) * 2048 + j0 + kb * 8, &buf[1024 + s4 * 256 + (t & ~63)]);
  }
}

__global__ __launch_bounds__(256, 2) void flash_fwd(
    const __bf16* __restrict__ Qp, const __bf16* __restrict__ Kp,
    const __bf16* __restrict__ Vt, const int* __restrict__ lenx,
    float* __restrict__ Out, float* __restrict__ Lb)
{
  __shared__ bf16x8 KV[4096];  // 2 stages x [K 0..1023 | V 1024..2047]; P overlays K of cur stage
  const int t = threadIdx.x, wid = t >> 6, lane = t & 63;
  const int g = lane >> 4, c = lane & 15;
  const int b = blockIdx.x & 1, qt = (blockIdx.x >> 1) & 31, h = blockIdx.x >> 6;
  const int len = lenx[b];
  const int row0 = qt * 128, wrow = wid * 32;
  const float SE = 0.03125f * 1.44269504f;

  stage_kv(Kp, Vt, b, h, 0, &KV[0], t);
  // Q fragments direct from global (one-time, L2/L3-resident)
  bf16x8 qf[2][4];
#pragma unroll
  for (int mb = 0; mb < 2; ++mb)
#pragma unroll
    for (int kc = 0; kc < 4; ++kc)
      qf[mb][kc] = *(const bf16x8*)(Qp + (size_t)(b * NQ + row0 + wrow + mb * 16 + c) * 1024 +
                                    h * 128 + (kc * 4 + g) * 8);

  floatx4 o[2][8] = {};
  float rs[2][4] = {};
  const int njt = (len + 63) >> 6;
  for (int jt = 0; jt < njt; ++jt) {
    const int j0 = jt * 64;
    bf16x8* base = &KV[(jt & 1) * 2048];
    if (jt + 1 < njt) { stage_kv(Kp, Vt, b, h, j0 + 64, &KV[((jt + 1) & 1) * 2048], t); WAITB(8); }
    else WAITB(0);
    floatx4 sa[2][4] = {};
#pragma unroll
    for (int kc = 0; kc < 4; ++kc)
#pragma unroll
      for (int nb = 0; nb < 4; ++nb) {
        bf16x8 kf = base[(nb * 16 + c) * 16 + ((kc * 4 + g) ^ c)];
#pragma unroll
        for (int mb = 0; mb < 2; ++mb)
          sa[mb][nb] = __builtin_amdgcn_mfma_f32_16x16x32_bf16(qf[mb][kc], kf, sa[mb][nb], 0, 0, 0);
      }
    LBAR();   // all waves done reading K region -> safe to overlay P
    // p = exp2(s*SE) (m==0: scores are O(1), no overflow); masked -> 0
    __bf16* psp = (__bf16*)&base[wid * 256];
#pragma unroll
    for (int nb = 0; nb < 4; ++nb) {
      bool valid = (j0 + nb * 16 + c) < len;
      int j = nb * 16 + c;
#pragma unroll
      for (int mb = 0; mb < 2; ++mb)
#pragma unroll
        for (int reg = 0; reg < 4; ++reg) {
          float p = __builtin_amdgcn_exp2f(sa[mb][nb][reg] * SE);
          p = valid ? p : 0.0f;
          rs[mb][reg] += p;
          int lr = mb * 16 + g * 4 + reg;
          psp[(lr * 8 + ((j >> 3) ^ (lr & 7))) * 8 + (j & 7)] = (__bf16)p;
        }
    }
#pragma unroll
    for (int kc = 0; kc < 2; ++kc) {
      bf16x8 pf[2];
#pragma unroll
      for (int mb = 0; mb < 2; ++mb)
        pf[mb] = base[wid * 256 + (mb * 16 + c) * 8 + ((kc * 4 + g) ^ (c & 7))];
#pragma unroll
      for (int db = 0; db < 8; ++db) {
        bf16x8 vf = base[1024 + (db * 16 + c) * 8 + ((kc * 4 + g) ^ (c & 7))];
#pragma unroll
        for (int mb = 0; mb < 2; ++mb)
          o[mb][db] = __builtin_amdgcn_mfma_f32_16x16x32_bf16(pf[mb], vf, o[mb][db], 0, 0, 0);
      }
    }
    BAR();    // all waves done with this stage before next prefetch overwrites it
  }
  // reduce l over the 16 c-lanes (row lives across c)
  float linv[2][4];
#pragma unroll
  for (int mb = 0; mb < 2; ++mb)
#pragma unroll
    for (int reg = 0; reg < 4; ++reg) {
      float s = rs[mb][reg];
#pragma unroll
      for (int off = 1; off < 16; off <<= 1) s += __shfl_xor(s, off);
      linv[mb][reg] = 1.0f / s;
    }
#pragma unroll
  for (int mb = 0; mb < 2; ++mb) {
    size_t orow0 = (size_t)(b * NQ + row0 + wrow + mb * 16);
#pragma unroll
    for (int db = 0; db < 8; ++db)
#pragma unroll
      for (int reg = 0; reg < 4; ++reg)
        Out[(orow0 + g * 4 + reg) * 1024 + h * 128 + db * 16 + c] = o[mb][db][reg] * linv[mb][reg];
    if (c == 0) {
      int sbase = (b * 8 + h) * NQ + row0 + wrow + mb * 16;
#pragma unroll
      for (int reg = 0; reg < 4; ++reg) Lb[sbase + g * 4 + reg] = linv[mb][reg];
    }
  }
}

// ---------------- Pass 2: attn2 — 128x128 tiles, 32-wide k stages, 4 blocks/CU ----------------
// Stage = [128 rows][32 k] of Q and K for one (head, quarter). LDS slot s (16B units)
// holds row r=s>>2, chunk ch=(s&3)^((s>>3)&3) (chunk = 16B = 8 bf16 of k).
// Read: slot = R*4 + (g ^ ((R>>1)&3)). Bank check across 8 lanes (R=R0+c, R0 even, g fixed):
// addr16 mod 8 = 4*(c&1) + (g ^ (v0 + (c>>1))) mod 4-distinct -> all 8 distinct, conflict-free.
__device__ __forceinline__ void stage_qk32(const __bf16* __restrict__ Qp, const __bf16* __restrict__ Kp,
                                           int b, int h, int kq, int i0, int j0, bf16x8* buf, int t) {
#pragma unroll
  for (int s2 = 0; s2 < 2; ++s2) {
    int s = s2 * 256 + t;
    int r = s >> 2, ch = (s & 3) ^ ((s >> 3) & 3);
    async_ld16(Qp + (size_t)(b * NQ + i0 + r) * 1024 + h * 128 + kq * 32 + ch * 8,
               &buf[s2 * 256 + (t & ~63)]);
    async_ld16(Kp + (size_t)(b * NK + j0 + r) * 1024 + h * 128 + kq * 32 + ch * 8,
               &buf[512 + s2 * 256 + (t & ~63)]);
  }
}

__global__ __launch_bounds__(256, 4) void attn_mean(
    const __bf16* __restrict__ Qp, const __bf16* __restrict__ Kp,
    const float* __restrict__ Lb, const int* __restrict__ lenx, float* __restrict__ A2)
{
  __shared__ bf16x8 QK[2048];   // 2 stages x [Q 0..511 | K 512..1023] (16 KB/stage)
  __shared__ float Lsh[1024];   // linv for 8 heads x 128 rows
  const int t = threadIdx.x, wid = t >> 6, lane = t & 63;
  const int g = lane >> 4, c = lane & 15;
  const int wm = wid >> 1, wn = wid & 1;
  const int b = blockIdx.x & 1, jt = (blockIdx.x >> 1) & 15, it = blockIdx.x >> 5;
  const int len = lenx[b];
  const int j0 = jt * 128, i0 = it * 128;
  size_t arow0 = (size_t)(b * NQ + i0);
  const float SE = 0.03125f * 1.44269504f;
  if (j0 >= len) {
    float4 z = {0.f, 0.f, 0.f, 0.f};
    for (int q = t; q < 4096; q += 256) {
      int r = q >> 5, cb = q & 31;
      *(float4*)(A2 + (arow0 + r) * 2048 + j0 + cb * 4) = z;
    }
    return;
  }
  {
    int hh = t >> 5, uu = t & 31;
    async_ld16(Lb + (size_t)(b * 8 + hh) * NQ + i0 + uu * 4, &Lsh[(t & ~63) * 4]);
  }
  stage_qk32(Qp, Kp, b, 0, 0, i0, j0, &QK[0], t);
  floatx4 a2[4][4] = {};
  floatx4 sa[4][4];
  for (int st = 0; st < 32; ++st) {
    const int h = st >> 2, kq = st & 3;
    bf16x8* base = &QK[(st & 1) * 1024];
    if (st + 1 < 32) {
      stage_qk32(Qp, Kp, b, (st + 1) >> 2, (st + 1) & 3, i0, j0, &QK[((st + 1) & 1) * 1024], t);
      WAITB(4);
    } else WAITB(0);
    if (kq == 0) {
#pragma unroll
      for (int mb = 0; mb < 4; ++mb)
#pragma unroll
        for (int nb = 0; nb < 4; ++nb) sa[mb][nb] = floatx4{0.f, 0.f, 0.f, 0.f};
    }
    bf16x8 qa[4], ka[4];
#pragma unroll
    for (int mb = 0; mb < 4; ++mb) {
      int R = wm * 64 + mb * 16 + c;
      qa[mb] = base[R * 4 + (g ^ ((R >> 1) & 3))];
    }
#pragma unroll
    for (int nb = 0; nb < 4; ++nb) {
      int R = wn * 64 + nb * 16 + c;
      ka[nb] = base[512 + R * 4 + (g ^ ((R >> 1) & 3))];
    }
#pragma unroll
    for (int mb = 0; mb < 4; ++mb)
#pragma unroll
      for (int nb = 0; nb < 4; ++nb)
        sa[mb][nb] = __builtin_amdgcn_mfma_f32_16x16x32_bf16(qa[mb], ka[nb], sa[mb][nb], 0, 0, 0);
    if (kq == 3) {
#pragma unroll
      for (int mb = 0; mb < 4; ++mb) {
        floatx4 lrv = *(const floatx4*)&Lsh[h * 128 + wm * 64 + mb * 16 + g * 4];
#pragma unroll
        for (int nb = 0; nb < 4; ++nb) {
          bool valid = (j0 + wn * 64 + nb * 16 + c) < len;
#pragma unroll
          for (int reg = 0; reg < 4; ++reg) {
            float p = __builtin_amdgcn_exp2f(sa[mb][nb][reg] * SE) * lrv[reg];
            a2[mb][nb][reg] += valid ? p : 0.0f;
          }
        }
      }
    }
    BAR();
  }
#pragma unroll
  for (int mb = 0; mb < 4; ++mb)
#pragma unroll
    for (int nb = 0; nb < 4; ++nb)
#pragma unroll
      for (int reg = 0; reg < 4; ++reg)
        A2[(arow0 + wm * 64 + mb * 16 + g * 4 + reg) * 2048 + j0 + wn * 64 + nb * 16 + c] =
            a2[mb][nb][reg] * 0.125f;
}

extern "C" void kernel_launch(void* const* d_in, const int* in_sizes, int n_in,
                              void* d_out, int out_size, void* d_ws, size_t ws_size,
                              hipStream_t stream) {
  const float* queries = (const float*)d_in[0];
  const float* keys    = (const float*)d_in[1];
  const float* values  = (const float*)d_in[2];
  const float* Wq = (const float*)d_in[3];
  const float* bq = (const float*)d_in[4];
  const float* Wk = (const float*)d_in[5];
  const float* bk = (const float*)d_in[6];
  const float* Wv = (const float*)d_in[7];
  const float* bv = (const float*)d_in[8];
  const int* lenx = (const int*)d_in[9];

  char* ws = (char*)d_ws;
  __bf16* Wbf = (__bf16*)ws;                   // 6 MB  [3,1024,1024] bf16
  __bf16* Qp  = (__bf16*)(ws + 6291456);       // 16 MB [2,4096,1024]
  __bf16* Kp  = (__bf16*)(ws + 23068672);      // 8 MB  [2,2048,1024]
  __bf16* Vt  = (__bf16*)(ws + 31457280);      // 8 MB  [16,128,2048]
  float*  Lb  = (float*)(ws + 39845888);       // 256 KB [16,4096]

  float* Out = (float*)d_out;
  float* A2  = Out + (size_t)2 * 4096 * 1024;

  // bf16 activations: scratch in the A2 output region (32 MB of its 64 MB),
  // dead after gemm_all; attn_mean overwrites all of A2 afterwards.
  __bf16* Xbf = (__bf16*)A2;
  const __bf16* Xqb = Xbf;
  const __bf16* Xkb = Xbf + 8388608;
  const __bf16* Xvb = Xbf + 12582912;

  cvt_all<<<19456, 256, 0, stream>>>(Wq, Wk, Wv, queries, keys, values, Wbf, Xbf);
  gemm_all<<<dim3(128, 8), 256, 0, stream>>>(Xqb, Xkb, Xvb, Wbf, bq, bk, bv, Qp, Kp, Vt);
  flash_fwd<<<512, 256, 0, stream>>>(Qp, Kp, Vt, lenx, Out, Lb);
  attn_mean<<<1024, 256, 0, stream>>>(Qp, Kp, Lb, lenx, A2);
}

// Round 4
// 330.881 us; speedup vs baseline: 1.2335x; 1.2335x over previous
//
#include <hip/hip_runtime.h>
#include <hip/hip_bf16.h>
#include <stdint.h>

#define NQ 4096
#define NK 2048

typedef __bf16 bf16x8 __attribute__((ext_vector_type(8)));
typedef __bf16 bf16x4 __attribute__((ext_vector_type(4)));
typedef float floatx4 __attribute__((ext_vector_type(4)));

// Raw barrier + partial vmcnt wait: prefetch loads stay in flight across the barrier.
#define WAITB(N) asm volatile("s_waitcnt vmcnt(" #N ")\n\ts_barrier" ::: "memory")
#define BAR()    asm volatile("s_barrier" ::: "memory")
#define LBAR()   asm volatile("s_waitcnt lgkmcnt(0)\n\ts_barrier" ::: "memory")

__device__ __forceinline__ void async_ld16(const void* g, void* l) {
  __builtin_amdgcn_global_load_lds((const __attribute__((address_space(1))) void*)g,
                                   (__attribute__((address_space(3))) void*)l, 16, 0, 0);
}

// ---------------- Convert weights AND activations f32 -> bf16 ----------------
__global__ __launch_bounds__(256) void cvt_all(
    const float* __restrict__ Wq, const float* __restrict__ Wk, const float* __restrict__ Wv,
    const float* __restrict__ Xq, const float* __restrict__ Xk, const float* __restrict__ Xv,
    __bf16* __restrict__ Wbf, __bf16* __restrict__ Xbf)
{
  int bid = blockIdx.x;
  const float* src; __bf16* dst; int lb;
  if (bid < 3072)       { int seg = bid >> 10;
                          src = seg == 0 ? Wq : (seg == 1 ? Wk : Wv);
                          dst = Wbf + (size_t)seg * 1048576; lb = bid & 1023; }
  else if (bid < 11264) { src = Xq; dst = Xbf;            lb = bid - 3072;  }  // 8192 blocks
  else if (bid < 15360) { src = Xk; dst = Xbf + 8388608;  lb = bid - 11264; }  // 4096 blocks
  else                  { src = Xv; dst = Xbf + 12582912; lb = bid - 15360; }  // 4096 blocks
  int idx = (lb * 256 + threadIdx.x) * 4;
  float4 v = *(const float4*)(src + idx);
  bf16x4 o;
  o[0] = (__bf16)v.x; o[1] = (__bf16)v.y; o[2] = (__bf16)v.z; o[3] = (__bf16)v.w;
  *(bf16x4*)(dst + idx) = o;
}

// ---------------- Merged projection GEMM: Q/K/V in one launch, pure bf16 ----------------
__device__ __forceinline__ void stage_ab(const __bf16* __restrict__ A, const __bf16* __restrict__ W,
                                         int bm, int bn, int k0, bf16x8* As, bf16x8* Bs, int t) {
#pragma unroll
  for (int s2 = 0; s2 < 2; ++s2) {
    int s = s2 * 256 + t;
    int r = s >> 2, kb = (s & 3) ^ ((r >> 1) & 3);   // 128 rows x 4 chunks of 8 bf16
    async_ld16(A + (size_t)(bm + r) * 1024 + k0 + kb * 8, &As[s2 * 256 + (t & ~63)]);
    async_ld16(W + (size_t)(bn + r) * 1024 + k0 + kb * 8, &Bs[s2 * 256 + (t & ~63)]);
  }
}

__global__ __launch_bounds__(256, 4) void gemm_all(
    const __bf16* __restrict__ Xq, const __bf16* __restrict__ Xk, const __bf16* __restrict__ Xv,
    const __bf16* __restrict__ Wbf,
    const float* __restrict__ bq, const float* __restrict__ bk, const float* __restrict__ bv,
    __bf16* __restrict__ Qp, __bf16* __restrict__ Kp, __bf16* __restrict__ Vt)
{
  __shared__ bf16x8 As[2][512];
  __shared__ bf16x8 Bs[2][512];
  const int t = threadIdx.x, wid = t >> 6, lane = t & 63;
  const int g = lane >> 4, c = lane & 15;
  const int mt = blockIdx.x;
  const __bf16* A; const __bf16* W; const float* bias; __bf16* Y; int bm; bool vmode;
  if (mt < 64)      { A = Xq; W = Wbf;           bias = bq; Y = Qp; bm = mt * 128;        vmode = false; }
  else if (mt < 96) { A = Xk; W = Wbf + 1048576; bias = bk; Y = Kp; bm = (mt - 64) * 128; vmode = false; }
  else              { A = Xv; W = Wbf + 2097152; bias = bv; Y = Vt; bm = (mt - 96) * 128; vmode = true;  }
  const int bn = blockIdx.y * 128;
  const int m_off = (wid >> 1) * 64, n_off = (wid & 1) * 64;
  floatx4 acc[4][4] = {};
  const int swz = g ^ ((c >> 1) & 3);
  stage_ab(A, W, bm, bn, 0, &As[0][0], &Bs[0][0], t);
  for (int k0 = 0; k0 < 1024; k0 += 32) {
    int cur = (k0 >> 5) & 1;
    if (k0 + 32 < 1024) { stage_ab(A, W, bm, bn, k0 + 32, &As[cur ^ 1][0], &Bs[cur ^ 1][0], t); WAITB(4); }
    else WAITB(0);
    bf16x8 af[4], bfr[4];
#pragma unroll
    for (int mb = 0; mb < 4; ++mb) af[mb] = As[cur][(m_off + mb * 16 + c) * 4 + swz];
#pragma unroll
    for (int nb = 0; nb < 4; ++nb) bfr[nb] = Bs[cur][(n_off + nb * 16 + c) * 4 + swz];
#pragma unroll
    for (int mb = 0; mb < 4; ++mb)
#pragma unroll
      for (int nb = 0; nb < 4; ++nb)
        acc[mb][nb] = __builtin_amdgcn_mfma_f32_16x16x32_bf16(af[mb], bfr[nb], acc[mb][nb], 0, 0, 0);
    BAR();
  }
#pragma unroll
  for (int nb = 0; nb < 4; ++nb) {
    int col = bn + n_off + nb * 16 + c;
    float bv2 = bias[col];
    if (!vmode) {
#pragma unroll
      for (int mb = 0; mb < 4; ++mb)
#pragma unroll
        for (int reg = 0; reg < 4; ++reg) {
          int row = bm + m_off + mb * 16 + g * 4 + reg;
          Y[(size_t)row * 1024 + col] = (__bf16)(acc[mb][nb][reg] + bv2);
        }
    } else {
      // Vt[(b*8+h)*128 + d][j]; col = h*128+d, row = b*2048+j. 4 regs = 4 consecutive j.
#pragma unroll
      for (int mb = 0; mb < 4; ++mb) {
        int row0 = bm + m_off + mb * 16 + g * 4;
        bf16x4 pv;
#pragma unroll
        for (int reg = 0; reg < 4; ++reg) pv[reg] = (__bf16)(acc[mb][nb][reg] + bv2);
        *(bf16x4*)&Y[(size_t)((row0 >> 11) * 1024 + col) * 2048 + (row0 & 2047)] = pv;
      }
    }
  }
}

// ---------------- Flash pass 1: m==0 softmax, 128-row Q tile, P overlays K region ----------
__device__ __forceinline__ void stage_kv(const __bf16* __restrict__ Kp, const __bf16* __restrict__ Vt,
                                         int b, int h, int j0, bf16x8* buf, int t) {
#pragma unroll
  for (int s4 = 0; s4 < 4; ++s4) {
    int s = s4 * 256 + t;
    int j = s >> 4, db = (s & 15) ^ (j & 15);     // K: 64 rows(j) x 16 chunks(d)
    async_ld16(Kp + (size_t)(b * NK + j0 + j) * 1024 + h * 128 + db * 8, &buf[s4 * 256 + (t & ~63)]);
    int d = s >> 3, kb = (s & 7) ^ (d & 7);       // V: 128 rows(d) x 8 chunks(j)
    async_ld16(Vt + (size_t)((b * 8 + h) * 128 + d) * 2048 + j0 + kb * 8, &buf[1024 + s4 * 256 + (t & ~63)]);
  }
}

__global__ __launch_bounds__(256, 2) void flash_fwd(
    const __bf16* __restrict__ Qp, const __bf16* __restrict__ Kp,
    const __bf16* __restrict__ Vt, const int* __restrict__ lenx,
    float* __restrict__ Out, float* __restrict__ Lb)
{
  __shared__ bf16x8 KV[4096];  // 2 stages x [K 0..1023 | V 1024..2047]; P overlays K of cur stage
  const int t = threadIdx.x, wid = t >> 6, lane = t & 63;
  const int g = lane >> 4, c = lane & 15;
  const int b = blockIdx.x & 1, qt = (blockIdx.x >> 1) & 31, h = blockIdx.x >> 6;
  const int len = lenx[b];
  const int row0 = qt * 128, wrow = wid * 32;
  const float SE = 0.03125f * 1.44269504f;

  stage_kv(Kp, Vt, b, h, 0, &KV[0], t);
  // Q fragments direct from global (one-time, L2/L3-resident)
  bf16x8 qf[2][4];
#pragma unroll
  for (int mb = 0; mb < 2; ++mb)
#pragma unroll
    for (int kc = 0; kc < 4; ++kc)
      qf[mb][kc] = *(const bf16x8*)(Qp + (size_t)(b * NQ + row0 + wrow + mb * 16 + c) * 1024 +
                                    h * 128 + (kc * 4 + g) * 8);

  floatx4 o[2][8] = {};
  float rs[2][4] = {};
  const int njt = (len + 63) >> 6;
  for (int jt = 0; jt < njt; ++jt) {
    const int j0 = jt * 64;
    bf16x8* base = &KV[(jt & 1) * 2048];
    if (jt + 1 < njt) { stage_kv(Kp, Vt, b, h, j0 + 64, &KV[((jt + 1) & 1) * 2048], t); WAITB(8); }
    else WAITB(0);
    floatx4 sa[2][4] = {};
#pragma unroll
    for (int kc = 0; kc < 4; ++kc)
#pragma unroll
      for (int nb = 0; nb < 4; ++nb) {
        bf16x8 kf = base[(nb * 16 + c) * 16 + ((kc * 4 + g) ^ c)];
#pragma unroll
        for (int mb = 0; mb < 2; ++mb)
          sa[mb][nb] = __builtin_amdgcn_mfma_f32_16x16x32_bf16(qf[mb][kc], kf, sa[mb][nb], 0, 0, 0);
      }
    LBAR();   // all waves done reading K region -> safe to overlay P
    // p = exp2(s*SE) (m==0: scores are O(1), no overflow); masked -> 0
    __bf16* psp = (__bf16*)&base[wid * 256];
#pragma unroll
    for (int nb = 0; nb < 4; ++nb) {
      bool valid = (j0 + nb * 16 + c) < len;
      int j = nb * 16 + c;
#pragma unroll
      for (int mb = 0; mb < 2; ++mb)
#pragma unroll
        for (int reg = 0; reg < 4; ++reg) {
          float p = __builtin_amdgcn_exp2f(sa[mb][nb][reg] * SE);
          p = valid ? p : 0.0f;
          rs[mb][reg] += p;
          int lr = mb * 16 + g * 4 + reg;
          psp[(lr * 8 + ((j >> 3) ^ (lr & 7))) * 8 + (j & 7)] = (__bf16)p;
        }
    }
#pragma unroll
    for (int kc = 0; kc < 2; ++kc) {
      bf16x8 pf[2];
#pragma unroll
      for (int mb = 0; mb < 2; ++mb)
        pf[mb] = base[wid * 256 + (mb * 16 + c) * 8 + ((kc * 4 + g) ^ (c & 7))];
#pragma unroll
      for (int db = 0; db < 8; ++db) {
        bf16x8 vf = base[1024 + (db * 16 + c) * 8 + ((kc * 4 + g) ^ (c & 7))];
#pragma unroll
        for (int mb = 0; mb < 2; ++mb)
          o[mb][db] = __builtin_amdgcn_mfma_f32_16x16x32_bf16(pf[mb], vf, o[mb][db], 0, 0, 0);
      }
    }
    BAR();    // all waves done with this stage before next prefetch overwrites it
  }
  // reduce l over the 16 c-lanes (row lives across c)
  float linv[2][4];
#pragma unroll
  for (int mb = 0; mb < 2; ++mb)
#pragma unroll
    for (int reg = 0; reg < 4; ++reg) {
      float s = rs[mb][reg];
#pragma unroll
      for (int off = 1; off < 16; off <<= 1) s += __shfl_xor(s, off);
      linv[mb][reg] = 1.0f / s;
    }
#pragma unroll
  for (int mb = 0; mb < 2; ++mb) {
    size_t orow0 = (size_t)(b * NQ + row0 + wrow + mb * 16);
#pragma unroll
    for (int db = 0; db < 8; ++db)
#pragma unroll
      for (int reg = 0; reg < 4; ++reg)
        Out[(orow0 + g * 4 + reg) * 1024 + h * 128 + db * 16 + c] = o[mb][db][reg] * linv[mb][reg];
    if (c == 0) {
      int sbase = (b * 8 + h) * NQ + row0 + wrow + mb * 16;
#pragma unroll
      for (int reg = 0; reg < 4; ++reg) Lb[sbase + g * 4 + reg] = linv[mb][reg];
    }
  }
}

// ---------------- Pass 2: attn2 — 128x64 block tile, wave 64x32, 32-wide k stages ----------
// Register budget: a2[4][2]+sa[4][2]=64 + qa[4]+ka[2]=24 + addr ~20 => fits 128-reg cap
// (launch_bounds(256,4)) WITHOUT spill (round-3 spilled with 64x64 tile: 128 acc regs).
// LDS: 2 stages x (Q 128x32 = 8KB + K 64x32 = 4KB) + Lsh 4KB = 28 KB -> 4 blocks/CU.
// Slot layout (16B units): slot = r*4 + (ch ^ ((r>>1)&3)); read slot = R*4 + (g^((R>>1)&3))
// -> conflict-free (round-3 measured SQ_LDS_BANK_CONFLICT = 0).
__device__ __forceinline__ void stage_qk32(const __bf16* __restrict__ Qp, const __bf16* __restrict__ Kp,
                                           int b, int h, int kq, int i0, int j0, bf16x8* buf, int t) {
#pragma unroll
  for (int s2 = 0; s2 < 2; ++s2) {
    int s = s2 * 256 + t;
    int r = s >> 2, ch = (s & 3) ^ ((s >> 3) & 3);
    async_ld16(Qp + (size_t)(b * NQ + i0 + r) * 1024 + h * 128 + kq * 32 + ch * 8,
               &buf[s2 * 256 + (t & ~63)]);
  }
  {
    int r = t >> 2, ch = (t & 3) ^ ((t >> 3) & 3);
    async_ld16(Kp + (size_t)(b * NK + j0 + r) * 1024 + h * 128 + kq * 32 + ch * 8,
               &buf[512 + (t & ~63)]);
  }
}

__global__ __launch_bounds__(256, 4) void attn_mean(
    const __bf16* __restrict__ Qp, const __bf16* __restrict__ Kp,
    const float* __restrict__ Lb, const int* __restrict__ lenx, float* __restrict__ A2)
{
  __shared__ bf16x8 QK[1536];   // 2 stages x [Q 0..511 | K 512..767] (12 KB/stage)
  __shared__ float Lsh[1024];   // linv for 8 heads x 128 rows
  const int t = threadIdx.x, wid = t >> 6, lane = t & 63;
  const int g = lane >> 4, c = lane & 15;
  const int wm = wid >> 1, wn = wid & 1;
  const int b = blockIdx.x & 1, jt = (blockIdx.x >> 1) & 31, it = blockIdx.x >> 6;
  const int len = lenx[b];
  const int j0 = jt * 64, i0 = it * 128;
  size_t arow0 = (size_t)(b * NQ + i0);
  const float SE = 0.03125f * 1.44269504f;
  if (j0 >= len) {
    float4 z = {0.f, 0.f, 0.f, 0.f};
    for (int q = t; q < 2048; q += 256) {
      int r = q >> 4, cb = q & 15;
      *(float4*)(A2 + (arow0 + r) * 2048 + j0 + cb * 4) = z;
    }
    return;
  }
  {
    int hh = t >> 5, uu = t & 31;
    async_ld16(Lb + (size_t)(b * 8 + hh) * NQ + i0 + uu * 4, &Lsh[(t & ~63) * 4]);
  }
  stage_qk32(Qp, Kp, b, 0, 0, i0, j0, &QK[0], t);
  floatx4 a2[4][2] = {};
  floatx4 sa[4][2];
  for (int st = 0; st < 32; ++st) {
    const int h = st >> 2, kq = st & 3;
    bf16x8* base = &QK[(st & 1) * 768];
    if (st + 1 < 32) {
      stage_qk32(Qp, Kp, b, (st + 1) >> 2, (st + 1) & 3, i0, j0, &QK[((st + 1) & 1) * 768], t);
      WAITB(3);
    } else WAITB(0);
    if (kq == 0) {
#pragma unroll
      for (int mb = 0; mb < 4; ++mb)
#pragma unroll
        for (int nb = 0; nb < 2; ++nb) sa[mb][nb] = floatx4{0.f, 0.f, 0.f, 0.f};
    }
    bf16x8 qa[4], ka[2];
#pragma unroll
    for (int mb = 0; mb < 4; ++mb) {
      int R = wm * 64 + mb * 16 + c;
      qa[mb] = base[R * 4 + (g ^ ((R >> 1) & 3))];
    }
#pragma unroll
    for (int nb = 0; nb < 2; ++nb) {
      int R = wn * 32 + nb * 16 + c;
      ka[nb] = base[512 + R * 4 + (g ^ ((R >> 1) & 3))];
    }
#pragma unroll
    for (int mb = 0; mb < 4; ++mb)
#pragma unroll
      for (int nb = 0; nb < 2; ++nb)
        sa[mb][nb] = __builtin_amdgcn_mfma_f32_16x16x32_bf16(qa[mb], ka[nb], sa[mb][nb], 0, 0, 0);
    if (kq == 3) {
#pragma unroll
      for (int mb = 0; mb < 4; ++mb) {
        floatx4 lrv = *(const floatx4*)&Lsh[h * 128 + wm * 64 + mb * 16 + g * 4];
#pragma unroll
        for (int nb = 0; nb < 2; ++nb) {
          bool valid = (j0 + wn * 32 + nb * 16 + c) < len;
#pragma unroll
          for (int reg = 0; reg < 4; ++reg) {
            float p = __builtin_amdgcn_exp2f(sa[mb][nb][reg] * SE) * lrv[reg];
            a2[mb][nb][reg] += valid ? p : 0.0f;
          }
        }
      }
    }
    BAR();
  }
#pragma unroll
  for (int mb = 0; mb < 4; ++mb)
#pragma unroll
    for (int nb = 0; nb < 2; ++nb)
#pragma unroll
      for (int reg = 0; reg < 4; ++reg)
        A2[(arow0 + wm * 64 + mb * 16 + g * 4 + reg) * 2048 + j0 + wn * 32 + nb * 16 + c] =
            a2[mb][nb][reg] * 0.125f;
}

extern "C" void kernel_launch(void* const* d_in, const int* in_sizes, int n_in,
                              void* d_out, int out_size, void* d_ws, size_t ws_size,
                              hipStream_t stream) {
  const float* queries = (const float*)d_in[0];
  const float* keys    = (const float*)d_in[1];
  const float* values  = (const float*)d_in[2];
  const float* Wq = (const float*)d_in[3];
  const float* bq = (const float*)d_in[4];
  const float* Wk = (const float*)d_in[5];
  const float* bk = (const float*)d_in[6];
  const float* Wv = (const float*)d_in[7];
  const float* bv = (const float*)d_in[8];
  const int* lenx = (const int*)d_in[9];

  char* ws = (char*)d_ws;
  __bf16* Wbf = (__bf16*)ws;                   // 6 MB  [3,1024,1024] bf16
  __bf16* Qp  = (__bf16*)(ws + 6291456);       // 16 MB [2,4096,1024]
  __bf16* Kp  = (__bf16*)(ws + 23068672);      // 8 MB  [2,2048,1024]
  __bf16* Vt  = (__bf16*)(ws + 31457280);      // 8 MB  [16,128,2048]
  float*  Lb  = (float*)(ws + 39845888);       // 256 KB [16,4096]

  float* Out = (float*)d_out;
  float* A2  = Out + (size_t)2 * 4096 * 1024;

  // bf16 activations: scratch in the A2 output region (32 MB of its 64 MB),
  // dead after gemm_all; attn_mean overwrites all of A2 afterwards.
  __bf16* Xbf = (__bf16*)A2;
  const __bf16* Xqb = Xbf;
  const __bf16* Xkb = Xbf + 8388608;
  const __bf16* Xvb = Xbf + 12582912;

  cvt_all<<<19456, 256, 0, stream>>>(Wq, Wk, Wv, queries, keys, values, Wbf, Xbf);
  gemm_all<<<dim3(128, 8), 256, 0, stream>>>(Xqb, Xkb, Xvb, Wbf, bq, bk, bv, Qp, Kp, Vt);
  flash_fwd<<<512, 256, 0, stream>>>(Qp, Kp, Vt, lenx, Out, Lb);
  attn_mean<<<2048, 256, 0, stream>>>(Qp, Kp, Lb, lenx, A2);
}

// Round 5
// 330.356 us; speedup vs baseline: 1.2355x; 1.0016x over previous
//
#include <hip/hip_runtime.h>
#include <hip/hip_bf16.h>
#include <stdint.h>

#define NQ 4096
#define NK 2048

typedef __bf16 bf16x8 __attribute__((ext_vector_type(8)));
typedef __bf16 bf16x4 __attribute__((ext_vector_type(4)));
typedef float floatx4 __attribute__((ext_vector_type(4)));

// Raw barrier + partial vmcnt wait: prefetch loads stay in flight across the barrier.
#define WAITB(N) asm volatile("s_waitcnt vmcnt(" #N ")\n\ts_barrier" ::: "memory")
#define BAR()    asm volatile("s_barrier" ::: "memory")

__device__ __forceinline__ void async_ld16(const void* g, void* l) {
  __builtin_amdgcn_global_load_lds((const __attribute__((address_space(1))) void*)g,
                                   (__attribute__((address_space(3))) void*)l, 16, 0, 0);
}

// ---------------- Convert weights AND activations f32 -> bf16 ----------------
__global__ __launch_bounds__(256) void cvt_all(
    const float* __restrict__ Wq, const float* __restrict__ Wk, const float* __restrict__ Wv,
    const float* __restrict__ Xq, const float* __restrict__ Xk, const float* __restrict__ Xv,
    __bf16* __restrict__ Wbf, __bf16* __restrict__ Xbf)
{
  int bid = blockIdx.x;
  const float* src; __bf16* dst; int lb;
  if (bid < 3072)       { int seg = bid >> 10;
                          src = seg == 0 ? Wq : (seg == 1 ? Wk : Wv);
                          dst = Wbf + (size_t)seg * 1048576; lb = bid & 1023; }
  else if (bid < 11264) { src = Xq; dst = Xbf;            lb = bid - 3072;  }  // 8192 blocks
  else if (bid < 15360) { src = Xk; dst = Xbf + 8388608;  lb = bid - 11264; }  // 4096 blocks
  else                  { src = Xv; dst = Xbf + 12582912; lb = bid - 15360; }  // 4096 blocks
  int idx = (lb * 256 + threadIdx.x) * 4;
  float4 v = *(const float4*)(src + idx);
  bf16x4 o;
  o[0] = (__bf16)v.x; o[1] = (__bf16)v.y; o[2] = (__bf16)v.z; o[3] = (__bf16)v.w;
  *(bf16x4*)(dst + idx) = o;
}

// ---------------- Merged projection GEMM: Q/K/V in one launch, pure bf16 ----------------
__device__ __forceinline__ void stage_ab(const __bf16* __restrict__ A, const __bf16* __restrict__ W,
                                         int bm, int bn, int k0, bf16x8* As, bf16x8* Bs, int t) {
#pragma unroll
  for (int s2 = 0; s2 < 2; ++s2) {
    int s = s2 * 256 + t;
    int r = s >> 2, kb = (s & 3) ^ ((r >> 1) & 3);   // 128 rows x 4 chunks of 8 bf16
    async_ld16(A + (size_t)(bm + r) * 1024 + k0 + kb * 8, &As[s2 * 256 + (t & ~63)]);
    async_ld16(W + (size_t)(bn + r) * 1024 + k0 + kb * 8, &Bs[s2 * 256 + (t & ~63)]);
  }
}

__global__ __launch_bounds__(256, 4) void gemm_all(
    const __bf16* __restrict__ Xq, const __bf16* __restrict__ Xk, const __bf16* __restrict__ Xv,
    const __bf16* __restrict__ Wbf,
    const float* __restrict__ bq, const float* __restrict__ bk, const float* __restrict__ bv,
    __bf16* __restrict__ Qp, __bf16* __restrict__ Kp, __bf16* __restrict__ Vt)
{
  __shared__ bf16x8 As[2][512];
  __shared__ bf16x8 Bs[2][512];
  const int t = threadIdx.x, wid = t >> 6, lane = t & 63;
  const int g = lane >> 4, c = lane & 15;
  const int mt = blockIdx.x;
  const __bf16* A; const __bf16* W; const float* bias; __bf16* Y; int bm; bool vmode;
  if (mt < 64)      { A = Xq; W = Wbf;           bias = bq; Y = Qp; bm = mt * 128;        vmode = false; }
  else if (mt < 96) { A = Xk; W = Wbf + 1048576; bias = bk; Y = Kp; bm = (mt - 64) * 128; vmode = false; }
  else              { A = Xv; W = Wbf + 2097152; bias = bv; Y = Vt; bm = (mt - 96) * 128; vmode = true;  }
  const int bn = blockIdx.y * 128;
  const int m_off = (wid >> 1) * 64, n_off = (wid & 1) * 64;
  floatx4 acc[4][4] = {};
  const int swz = g ^ ((c >> 1) & 3);
  stage_ab(A, W, bm, bn, 0, &As[0][0], &Bs[0][0], t);
  for (int k0 = 0; k0 < 1024; k0 += 32) {
    int cur = (k0 >> 5) & 1;
    if (k0 + 32 < 1024) { stage_ab(A, W, bm, bn, k0 + 32, &As[cur ^ 1][0], &Bs[cur ^ 1][0], t); WAITB(4); }
    else WAITB(0);
    bf16x8 af[4], bfr[4];
#pragma unroll
    for (int mb = 0; mb < 4; ++mb) af[mb] = As[cur][(m_off + mb * 16 + c) * 4 + swz];
#pragma unroll
    for (int nb = 0; nb < 4; ++nb) bfr[nb] = Bs[cur][(n_off + nb * 16 + c) * 4 + swz];
#pragma unroll
    for (int mb = 0; mb < 4; ++mb)
#pragma unroll
      for (int nb = 0; nb < 4; ++nb)
        acc[mb][nb] = __builtin_amdgcn_mfma_f32_16x16x32_bf16(af[mb], bfr[nb], acc[mb][nb], 0, 0, 0);
    BAR();
  }
#pragma unroll
  for (int nb = 0; nb < 4; ++nb) {
    int col = bn + n_off + nb * 16 + c;
    float bv2 = bias[col];
    if (!vmode) {
#pragma unroll
      for (int mb = 0; mb < 4; ++mb)
#pragma unroll
        for (int reg = 0; reg < 4; ++reg) {
          int row = bm + m_off + mb * 16 + g * 4 + reg;
          Y[(size_t)row * 1024 + col] = (__bf16)(acc[mb][nb][reg] + bv2);
        }
    } else {
      // Vt[(b*8+h)*128 + d][j]; col = h*128+d, row = b*2048+j. 4 regs = 4 consecutive j.
#pragma unroll
      for (int mb = 0; mb < 4; ++mb) {
        int row0 = bm + m_off + mb * 16 + g * 4;
        bf16x4 pv;
#pragma unroll
        for (int reg = 0; reg < 4; ++reg) pv[reg] = (__bf16)(acc[mb][nb][reg] + bv2);
        *(bf16x4*)&Y[(size_t)((row0 >> 11) * 1024 + col) * 2048 + (row0 & 2047)] = pv;
      }
    }
  }
}

// ---------------- Flash pass 1: m==0 softmax, 128-row Q tile ----------
// Single barrier per KV stage (T3-lite): {vmcnt(0)+barrier; issue prefetch; body}.
// P lives in a PRIVATE per-wave LDS region (no overlay of K) -> no mid-stage barrier;
// waves traverse QK/softmax/PV unsynchronized -> MFMA/VALU/LDS phases stagger across waves.
__device__ __forceinline__ void stage_kv(const __bf16* __restrict__ Kp, const __bf16* __restrict__ Vt,
                                         int b, int h, int j0, bf16x8* buf, int t) {
#pragma unroll
  for (int s4 = 0; s4 < 4; ++s4) {
    int s = s4 * 256 + t;
    int j = s >> 4, db = (s & 15) ^ (j & 15);     // K: 64 rows(j) x 16 chunks(d)
    async_ld16(Kp + (size_t)(b * NK + j0 + j) * 1024 + h * 128 + db * 8, &buf[s4 * 256 + (t & ~63)]);
    int d = s >> 3, kb = (s & 7) ^ (d & 7);       // V: 128 rows(d) x 8 chunks(j)
    async_ld16(Vt + (size_t)((b * 8 + h) * 128 + d) * 2048 + j0 + kb * 8, &buf[1024 + s4 * 256 + (t & ~63)]);
  }
}

__global__ __launch_bounds__(256, 2) void flash_fwd(
    const __bf16* __restrict__ Qp, const __bf16* __restrict__ Kp,
    const __bf16* __restrict__ Vt, const int* __restrict__ lenx,
    float* __restrict__ Out, float* __restrict__ Lb)
{
  __shared__ bf16x8 KV[4096];  // 2 stages x [K 0..1023 | V 1024..2047]
  __shared__ bf16x8 Pb[1024];  // private P: 4 waves x (32 rows x 64 cols bf16) = 16 KB
  const int t = threadIdx.x, wid = t >> 6, lane = t & 63;
  const int g = lane >> 4, c = lane & 15;
  const int b = blockIdx.x & 1, qt = (blockIdx.x >> 1) & 31, h = blockIdx.x >> 6;
  const int len = lenx[b];
  const int row0 = qt * 128, wrow = wid * 32;
  const float SE = 0.03125f * 1.44269504f;

  stage_kv(Kp, Vt, b, h, 0, &KV[0], t);
  // Q fragments direct from global (one-time, L2/L3-resident)
  bf16x8 qf[2][4];
#pragma unroll
  for (int mb = 0; mb < 2; ++mb)
#pragma unroll
    for (int kc = 0; kc < 4; ++kc)
      qf[mb][kc] = *(const bf16x8*)(Qp + (size_t)(b * NQ + row0 + wrow + mb * 16 + c) * 1024 +
                                    h * 128 + (kc * 4 + g) * 8);

  floatx4 o[2][8] = {};
  float rs[2][4] = {};
  const int njt = (len + 63) >> 6;
  for (int jt = 0; jt < njt; ++jt) {
    const int j0 = jt * 64;
    bf16x8* base = &KV[(jt & 1) * 2048];
    // Single sync point: own stage-jt loads drained (vmcnt 0) + all waves arrived
    // (=> all stage-jt loads complete AND all waves done reading buffer[(jt+1)&1]).
    WAITB(0);
    if (jt + 1 < njt) stage_kv(Kp, Vt, b, h, j0 + 64, &KV[((jt + 1) & 1) * 2048], t);
    floatx4 sa[2][4] = {};
    __builtin_amdgcn_s_setprio(1);
#pragma unroll
    for (int kc = 0; kc < 4; ++kc)
#pragma unroll
      for (int nb = 0; nb < 4; ++nb) {
        bf16x8 kf = base[(nb * 16 + c) * 16 + ((kc * 4 + g) ^ c)];
#pragma unroll
        for (int mb = 0; mb < 2; ++mb)
          sa[mb][nb] = __builtin_amdgcn_mfma_f32_16x16x32_bf16(qf[mb][kc], kf, sa[mb][nb], 0, 0, 0);
      }
    __builtin_amdgcn_s_setprio(0);
    // p = exp2(s*SE) (m==0: scores are O(1), no overflow); masked -> 0.
    // Write to this wave's private P region; compiler inserts lgkmcnt before pf reads.
    __bf16* psp = (__bf16*)&Pb[wid * 256];
#pragma unroll
    for (int nb = 0; nb < 4; ++nb) {
      bool valid = (j0 + nb * 16 + c) < len;
      int j = nb * 16 + c;
#pragma unroll
      for (int mb = 0; mb < 2; ++mb)
#pragma unroll
        for (int reg = 0; reg < 4; ++reg) {
          float p = __builtin_amdgcn_exp2f(sa[mb][nb][reg] * SE);
          p = valid ? p : 0.0f;
          rs[mb][reg] += p;
          int lr = mb * 16 + g * 4 + reg;
          psp[(lr * 8 + ((j >> 3) ^ (lr & 7))) * 8 + (j & 7)] = (__bf16)p;
        }
    }
    __builtin_amdgcn_s_setprio(1);
#pragma unroll
    for (int kc = 0; kc < 2; ++kc) {
      bf16x8 pf[2];
#pragma unroll
      for (int mb = 0; mb < 2; ++mb)
        pf[mb] = Pb[wid * 256 + (mb * 16 + c) * 8 + ((kc * 4 + g) ^ (c & 7))];
#pragma unroll
      for (int db = 0; db < 8; ++db) {
        bf16x8 vf = base[1024 + (db * 16 + c) * 8 + ((kc * 4 + g) ^ (c & 7))];
#pragma unroll
        for (int mb = 0; mb < 2; ++mb)
          o[mb][db] = __builtin_amdgcn_mfma_f32_16x16x32_bf16(pf[mb], vf, o[mb][db], 0, 0, 0);
      }
    }
    __builtin_amdgcn_s_setprio(0);
  }
  // reduce l over the 16 c-lanes (row lives across c)
  float linv[2][4];
#pragma unroll
  for (int mb = 0; mb < 2; ++mb)
#pragma unroll
    for (int reg = 0; reg < 4; ++reg) {
      float s = rs[mb][reg];
#pragma unroll
      for (int off = 1; off < 16; off <<= 1) s += __shfl_xor(s, off);
      linv[mb][reg] = 1.0f / s;
    }
#pragma unroll
  for (int mb = 0; mb < 2; ++mb) {
    size_t orow0 = (size_t)(b * NQ + row0 + wrow + mb * 16);
#pragma unroll
    for (int db = 0; db < 8; ++db)
#pragma unroll
      for (int reg = 0; reg < 4; ++reg)
        Out[(orow0 + g * 4 + reg) * 1024 + h * 128 + db * 16 + c] = o[mb][db][reg] * linv[mb][reg];
    if (c == 0) {
      int sbase = (b * 8 + h) * NQ + row0 + wrow + mb * 16;
#pragma unroll
      for (int reg = 0; reg < 4; ++reg) Lb[sbase + g * 4 + reg] = linv[mb][reg];
    }
  }
}

// ---------------- Pass 2: attn2 — 128x64 block tile, wave 64x32, 32-wide k stages ----------
// Register budget: a2[4][2]+sa[4][2]=64 + qa[4]+ka[2]=24 + addr ~20 => fits 128-reg cap
// (launch_bounds(256,4)) WITHOUT spill. LDS 28 KB -> 4 blocks/CU.
__device__ __forceinline__ void stage_qk32(const __bf16* __restrict__ Qp, const __bf16* __restrict__ Kp,
                                           int b, int h, int kq, int i0, int j0, bf16x8* buf, int t) {
#pragma unroll
  for (int s2 = 0; s2 < 2; ++s2) {
    int s = s2 * 256 + t;
    int r = s >> 2, ch = (s & 3) ^ ((s >> 3) & 3);
    async_ld16(Qp + (size_t)(b * NQ + i0 + r) * 1024 + h * 128 + kq * 32 + ch * 8,
               &buf[s2 * 256 + (t & ~63)]);
  }
  {
    int r = t >> 2, ch = (t & 3) ^ ((t >> 3) & 3);
    async_ld16(Kp + (size_t)(b * NK + j0 + r) * 1024 + h * 128 + kq * 32 + ch * 8,
               &buf[512 + (t & ~63)]);
  }
}

__global__ __launch_bounds__(256, 4) void attn_mean(
    const __bf16* __restrict__ Qp, const __bf16* __restrict__ Kp,
    const float* __restrict__ Lb, const int* __restrict__ lenx, float* __restrict__ A2)
{
  __shared__ bf16x8 QK[1536];   // 2 stages x [Q 0..511 | K 512..767] (12 KB/stage)
  __shared__ float Lsh[1024];   // linv for 8 heads x 128 rows
  const int t = threadIdx.x, wid = t >> 6, lane = t & 63;
  const int g = lane >> 4, c = lane & 15;
  const int wm = wid >> 1, wn = wid & 1;
  const int b = blockIdx.x & 1, jt = (blockIdx.x >> 1) & 31, it = blockIdx.x >> 6;
  const int len = lenx[b];
  const int j0 = jt * 64, i0 = it * 128;
  size_t arow0 = (size_t)(b * NQ + i0);
  const float SE = 0.03125f * 1.44269504f;
  if (j0 >= len) {
    float4 z = {0.f, 0.f, 0.f, 0.f};
    for (int q = t; q < 2048; q += 256) {
      int r = q >> 4, cb = q & 15;
      *(float4*)(A2 + (arow0 + r) * 2048 + j0 + cb * 4) = z;
    }
    return;
  }
  {
    int hh = t >> 5, uu = t & 31;
    async_ld16(Lb + (size_t)(b * 8 + hh) * NQ + i0 + uu * 4, &Lsh[(t & ~63) * 4]);
  }
  stage_qk32(Qp, Kp, b, 0, 0, i0, j0, &QK[0], t);
  floatx4 a2[4][2] = {};
  floatx4 sa[4][2];
  for (int st = 0; st < 32; ++st) {
    const int h = st >> 2, kq = st & 3;
    bf16x8* base = &QK[(st & 1) * 768];
    if (st + 1 < 32) {
      stage_qk32(Qp, Kp, b, (st + 1) >> 2, (st + 1) & 3, i0, j0, &QK[((st + 1) & 1) * 768], t);
      WAITB(3);
    } else WAITB(0);
    if (kq == 0) {
#pragma unroll
      for (int mb = 0; mb < 4; ++mb)
#pragma unroll
        for (int nb = 0; nb < 2; ++nb) sa[mb][nb] = floatx4{0.f, 0.f, 0.f, 0.f};
    }
    bf16x8 qa[4], ka[2];
#pragma unroll
    for (int mb = 0; mb < 4; ++mb) {
      int R = wm * 64 + mb * 16 + c;
      qa[mb] = base[R * 4 + (g ^ ((R >> 1) & 3))];
    }
#pragma unroll
    for (int nb = 0; nb < 2; ++nb) {
      int R = wn * 32 + nb * 16 + c;
      ka[nb] = base[512 + R * 4 + (g ^ ((R >> 1) & 3))];
    }
#pragma unroll
    for (int mb = 0; mb < 4; ++mb)
#pragma unroll
      for (int nb = 0; nb < 2; ++nb)
        sa[mb][nb] = __builtin_amdgcn_mfma_f32_16x16x32_bf16(qa[mb], ka[nb], sa[mb][nb], 0, 0, 0);
    if (kq == 3) {
#pragma unroll
      for (int mb = 0; mb < 4; ++mb) {
        floatx4 lrv = *(const floatx4*)&Lsh[h * 128 + wm * 64 + mb * 16 + g * 4];
#pragma unroll
        for (int nb = 0; nb < 2; ++nb) {
          bool valid = (j0 + wn * 32 + nb * 16 + c) < len;
#pragma unroll
          for (int reg = 0; reg < 4; ++reg) {
            float p = __builtin_amdgcn_exp2f(sa[mb][nb][reg] * SE) * lrv[reg];
            a2[mb][nb][reg] += valid ? p : 0.0f;
          }
        }
      }
    }
    BAR();
  }
#pragma unroll
  for (int mb = 0; mb < 4; ++mb)
#pragma unroll
    for (int nb = 0; nb < 2; ++nb)
#pragma unroll
      for (int reg = 0; reg < 4; ++reg)
        A2[(arow0 + wm * 64 + mb * 16 + g * 4 + reg) * 2048 + j0 + wn * 32 + nb * 16 + c] =
            a2[mb][nb][reg] * 0.125f;
}

extern "C" void kernel_launch(void* const* d_in, const int* in_sizes, int n_in,
                              void* d_out, int out_size, void* d_ws, size_t ws_size,
                              hipStream_t stream) {
  const float* queries = (const float*)d_in[0];
  const float* keys    = (const float*)d_in[1];
  const float* values  = (const float*)d_in[2];
  const float* Wq = (const float*)d_in[3];
  const float* bq = (const float*)d_in[4];
  const float* Wk = (const float*)d_in[5];
  const float* bk = (const float*)d_in[6];
  const float* Wv = (const float*)d_in[7];
  const float* bv = (const float*)d_in[8];
  const int* lenx = (const int*)d_in[9];

  char* ws = (char*)d_ws;
  __bf16* Wbf = (__bf16*)ws;                   // 6 MB  [3,1024,1024] bf16
  __bf16* Qp  = (__bf16*)(ws + 6291456);       // 16 MB [2,4096,1024]
  __bf16* Kp  = (__bf16*)(ws + 23068672);      // 8 MB  [2,2048,1024]
  __bf16* Vt  = (__bf16*)(ws + 31457280);      // 8 MB  [16,128,2048]
  float*  Lb  = (float*)(ws + 39845888);       // 256 KB [16,4096]

  float* Out = (float*)d_out;
  float* A2  = Out + (size_t)2 * 4096 * 1024;

  // bf16 activations: scratch in the A2 output region (32 MB of its 64 MB),
  // dead after gemm_all; attn_mean overwrites all of A2 afterwards.
  __bf16* Xbf = (__bf16*)A2;
  const __bf16* Xqb = Xbf;
  const __bf16* Xkb = Xbf + 8388608;
  const __bf16* Xvb = Xbf + 12582912;

  cvt_all<<<19456, 256, 0, stream>>>(Wq, Wk, Wv, queries, keys, values, Wbf, Xbf);
  gemm_all<<<dim3(128, 8), 256, 0, stream>>>(Xqb, Xkb, Xvb, Wbf, bq, bk, bv, Qp, Kp, Vt);
  flash_fwd<<<512, 256, 0, stream>>>(Qp, Kp, Vt, lenx, Out, Lb);
  attn_mean<<<2048, 256, 0, stream>>>(Qp, Kp, Lb, lenx, A2);
}